// Round 1
// baseline (465.265 us; speedup 1.0000x reference)
//
#include <hip/hip_runtime.h>
#include <math.h>

#define NQ 4096
#define NT 16384
#define DD 32
#define COLIDX 0
#define BIGF 1.0e10f

// Read a "bool" element from an input array whose storage width is unknown
// at compile time: w32==0 -> 1-byte bools, w32==1 -> int32 bools.
__device__ __forceinline__ int boolat(const void* p, long long idx, int w32) {
    if (w32) return ((const int*)p)[idx] != 0;
    return ((const unsigned char*)p)[idx] != 0;
}

// ---------------------------------------------------------------------------
// Prep kernel (1 block): detect bool storage width, scatter in_missing flags,
// pack potential column to uint8, compute col_mean.
// ---------------------------------------------------------------------------
__global__ __launch_bounds__(256) void prep_kernel(
    const void* __restrict__ nm,     // non_missing_fix_X (bool, Nt x D)
    const void* __restrict__ mk,     // mask_fit_X        (bool, Nt x D)
    const float* __restrict__ fitX,  // _fit_X            (f32,  Nt x D)
    const int* __restrict__ rmi,     // row_missing_idx   (i32,  Nq)
    int* __restrict__ wflag,
    float* __restrict__ cmean,
    unsigned char* __restrict__ inmiss,
    unsigned char* __restrict__ pot8)
{
    __shared__ int s_bad;
    __shared__ float s_c[256];
    __shared__ float s_m[256];
    const int tid = threadIdx.x;
    if (tid == 0) s_bad = 0;
    __syncthreads();

    // --- detect bool width: nm == ~mk elementwise by construction.
    // Under u8 storage, byte b of nm plus byte b of mk == 1 for all b.
    // Under i32 storage, bytes with b%4!=0 are 0 in both arrays -> sum 0.
    {
        const unsigned char* nm8 = (const unsigned char*)nm;
        const unsigned char* mk8 = (const unsigned char*)mk;
        int bad = 0;
        for (int b = tid; b < 4096; b += 256)
            if ((int)nm8[b] + (int)mk8[b] != 1) bad = 1;
        if (bad) atomicOr(&s_bad, 1);
    }
    __syncthreads();
    const int w32 = s_bad ? 1 : 0;
    if (tid == 0) *wflag = w32;

    // --- in_missing flags
    for (int i = tid; i < NQ; i += 256) inmiss[i] = 0;
    __syncthreads();
    for (int i = tid; i < NQ; i += 256) {
        int r = rmi[i];
        if (r >= 0 && r < NQ) inmiss[r] = 1;
    }

    // --- pack potential column
    for (int t = tid; t < NT; t += 256)
        pot8[t] = (unsigned char)boolat(nm, (long long)t * DD + COLIDX, w32);

    // --- column mean over observed fit values
    float cs = 0.0f, ms = 0.0f;
    for (int t = tid; t < NT; t += 256) {
        int obs = 1 - boolat(mk, (long long)t * DD + COLIDX, w32);
        if (obs) { cs += fitX[(long long)t * DD + COLIDX]; ms += 1.0f; }
    }
    s_c[tid] = cs; s_m[tid] = ms;
    __syncthreads();
    for (int s = 128; s > 0; s >>= 1) {
        if (tid < s) { s_c[tid] += s_c[tid + s]; s_m[tid] += s_m[tid + s]; }
        __syncthreads();
    }
    if (tid == 0) {
        float msum = s_m[0];
        *cmean = s_c[0] / (msum > 0.0f ? msum : 1.0f);
    }
}

// Merge two ascending-sorted 5-lists (key, idx) keeping the best 5.
// Tie-break: equal key -> lower index first (matches jax.lax.top_k).
__device__ __forceinline__ void merge5(float* v, int* id,
                                       const float* v2, const int* id2)
{
    float rv[5]; int rid[5];
    int a = 0, b = 0;
#pragma unroll
    for (int k = 0; k < 5; ++k) {
        bool takeA;
        if (a >= 5)      takeA = false;
        else if (b >= 5) takeA = true;
        else takeA = (v[a] < v2[b]) || (v[a] == v2[b] && id[a] < id2[b]);
        if (takeA) { rv[k] = v[a]; rid[k] = id[a]; ++a; }
        else       { rv[k] = v2[b]; rid[k] = id2[b]; ++b; }
    }
#pragma unroll
    for (int k = 0; k < 5; ++k) { v[k] = rv[k]; id[k] = rid[k]; }
}

// ---------------------------------------------------------------------------
// Main kernel: one block per query row.
// ---------------------------------------------------------------------------
__global__ __launch_bounds__(256) void impute_kernel(
    const float* __restrict__ X,
    const float* __restrict__ dist,
    const void* __restrict__ maskp,   // mask (bool, Nq x D)
    const void* __restrict__ mkfitp,  // mask_fit_X (bool, Nt x D)
    const float* __restrict__ fitX,
    const int* __restrict__ dmap,
    const int* __restrict__ wflagp,
    const float* __restrict__ cmeanp,
    const unsigned char* __restrict__ inmiss,
    const unsigned char* __restrict__ pot8,
    float* __restrict__ out)
{
    const int i = blockIdx.x;
    const int tid = threadIdx.x;

    // pass-through copy of the row (col 0 overwritten by thread 0 later)
    if (tid < DD)
        out[(long long)i * DD + tid] = X[(long long)i * DD + tid];

    const int w32 = *wflagp;
    const int q = dmap[i];
    const float4* drow = (const float4*)(dist + (long long)q * NT);

    float v[5]; int id[5];
#pragma unroll
    for (int k = 0; k < 5; ++k) { v[k] = __builtin_inff(); id[k] = 0x7fffffff; }
    bool hv = false;

    for (int it = 0; it < NT / 4 / 256; ++it) {   // 16 iterations
        const int vec = it * 256 + tid;
        const float4 dv = drow[vec];
        const uchar4 pv = *(const uchar4*)(pot8 + vec * 4);
        const float dj[4] = { dv.x, dv.y, dv.z, dv.w };
        const unsigned char pj[4] = { pv.x, pv.y, pv.z, pv.w };
#pragma unroll
        for (int j = 0; j < 4; ++j) {
            const int t = vec * 4 + j;
            const bool pot = pj[j] != 0;
            const bool nn = !(dj[j] != dj[j]);     // !isnan
            hv |= (pot && nn);
            const float key = pot ? (nn ? dj[j] : BIGF) : __builtin_inff();
            if (key < v[4]) {                      // strict: keeps earlier t on tie
                int p = 4;
                while (p > 0 && key < v[p - 1]) {
                    v[p] = v[p - 1]; id[p] = id[p - 1]; --p;
                }
                v[p] = key; id[p] = t;
            }
        }
    }

    // wave-level butterfly merge (64 lanes)
#pragma unroll
    for (int off = 32; off >= 1; off >>= 1) {
        float v2[5]; int id2[5];
#pragma unroll
        for (int k = 0; k < 5; ++k) {
            v2[k] = __shfl_down(v[k], off);
            id2[k] = __shfl_down(id[k], off);
        }
        merge5(v, id, v2, id2);
    }
    const bool whv = __any(hv);

    __shared__ float sv[4][5];
    __shared__ int   sid[4][5];
    __shared__ int   shv[4];
    const int wave = tid >> 6;
    const int lane = tid & 63;
    if (lane == 0) {
#pragma unroll
        for (int k = 0; k < 5; ++k) { sv[wave][k] = v[k]; sid[wave][k] = id[k]; }
        shv[wave] = whv ? 1 : 0;
    }
    __syncthreads();

    if (tid == 0) {
        for (int wv = 1; wv < 4; ++wv) {
            float v2[5]; int id2[5];
#pragma unroll
            for (int k = 0; k < 5; ++k) { v2[k] = sv[wv][k]; id2[k] = sid[wv][k]; }
            merge5(v, id, v2, id2);
        }
        const bool has_valid = (shv[0] | shv[1] | shv[2] | shv[3]) != 0;
        const bool receiver =
            inmiss[i] && boolat(maskp, (long long)i * DD + COLIDX, w32);

        float val;
        if (!receiver) {
            val = X[(long long)i * DD + COLIDX];
        } else if (!has_valid) {
            val = *cmeanp;
        } else {
            float wk[5], dnr[5], dmv[5], vld[5];
            bool infrow = false;
#pragma unroll
            for (int k = 0; k < 5; ++k) {
                const int idx = id[k];
                const bool ok = (idx >= 0) && (idx < NT);
                const float key = v[k];
                // reconstruct d_pot: key==BIGF means original was NaN
                const float dpot = (key == BIGF) ? __builtin_nanf("") : key;
                const float t = 1.0f / dpot;   // 0 -> inf, inf -> 0, NaN -> NaN
                wk[k] = ok ? t : 0.0f;
                if (ok && isinf(t)) infrow = true;
                dnr[k] = ok ? fitX[(long long)idx * DD + COLIDX] : 0.0f;
                dmv[k] = ok ? (1.0f - (float)boolat(mkfitp, (long long)idx * DD + COLIDX, w32))
                            : 0.0f;
                vld[k] = ok ? (float)pot8[idx] : 0.0f;
            }
            if (infrow) {
#pragma unroll
                for (int k = 0; k < 5; ++k) wk[k] = isinf(wk[k]) ? 1.0f : 0.0f;
            }
#pragma unroll
            for (int k = 0; k < 5; ++k) if (wk[k] != wk[k]) wk[k] = 0.0f;

            float wsum = 0.0f, vsum = 0.0f;
#pragma unroll
            for (int k = 0; k < 5; ++k) {
                const float nw = dmv[k] * wk[k] * vld[k];
                wsum += nw;
                vsum += dnr[k] * nw;
            }
            const float div = (wsum == 0.0f) ? 1.0f : wsum;
            val = vsum / div;
        }
        out[(long long)i * DD + COLIDX] = val;
    }
}

extern "C" void kernel_launch(void* const* d_in, const int* in_sizes, int n_in,
                              void* d_out, int out_size, void* d_ws, size_t ws_size,
                              hipStream_t stream) {
    const float* X     = (const float*)d_in[0];
    const float* dist  = (const float*)d_in[1];
    const void*  nm    = d_in[2];   // non_missing_fix_X (bool)
    const void*  mkfit = d_in[3];   // mask_fit_X (bool)
    const int*   dmap  = (const int*)d_in[4];
    const void*  maskp = d_in[5];   // mask (bool)
    const int*   rmi   = (const int*)d_in[6];
    const float* fitX  = (const float*)d_in[7];
    float* out = (float*)d_out;

    int*   wflag  = (int*)d_ws;
    float* cmean  = (float*)((char*)d_ws + 4);
    unsigned char* inmiss = (unsigned char*)d_ws + 8;
    unsigned char* pot8   = (unsigned char*)d_ws + 8 + NQ;

    prep_kernel<<<1, 256, 0, stream>>>(nm, mkfit, fitX, rmi,
                                       wflag, cmean, inmiss, pot8);
    impute_kernel<<<NQ, 256, 0, stream>>>(X, dist, maskp, mkfit, fitX, dmap,
                                          wflag, cmean, inmiss, pot8, out);
}

// Round 2
// 429.822 us; speedup vs baseline: 1.0825x; 1.0825x over previous
//
#include <hip/hip_runtime.h>
#include <math.h>

#define NQ 4096
#define NT 16384
#define DD 32
#define COLIDX 0
#define BIGF 1.0e10f
#define INFF __builtin_inff()

// Read a "bool" element from an input array whose storage width is unknown
// at compile time: w32==0 -> 1-byte bools, w32==1 -> int32 bools.
__device__ __forceinline__ int boolat(const void* p, long long idx, int w32) {
    if (w32) return ((const int*)p)[idx] != 0;
    return ((const unsigned char*)p)[idx] != 0;
}

// Per-block bool-width detect: nm == ~mk elementwise by construction.
// u8 storage: nm8[b]+mk8[b]==1 for every byte. i32: bytes b%4!=0 are 0+0.
__device__ __forceinline__ int detect_w32(const void* nm, const void* mk,
                                          int tid, int* s_bad) {
    if (tid == 0) *s_bad = 0;
    __syncthreads();
    const unsigned char* nm8 = (const unsigned char*)nm;
    const unsigned char* mk8 = (const unsigned char*)mk;
    int bad = 0;
    for (int b = tid; b < 4096; b += 256)
        if ((int)nm8[b] + (int)mk8[b] != 1) bad = 1;
    if (bad) atomicOr(s_bad, 1);
    __syncthreads();
    return *s_bad ? 1 : 0;
}

// ---------------------------------------------------------------------------
// prep1: 64 blocks x 256 threads — one thread per fit row t.
// pot8 pack, per-block colmean partials, inmiss clear, wflag.
// ---------------------------------------------------------------------------
__global__ __launch_bounds__(256) void prep1_kernel(
    const void* __restrict__ nm, const void* __restrict__ mk,
    const float* __restrict__ fitX,
    int* __restrict__ wflag, float* __restrict__ partial,
    unsigned char* __restrict__ inmiss, unsigned char* __restrict__ pot8)
{
    __shared__ int s_bad;
    __shared__ float sc[256], sm[256];
    const int tid = threadIdx.x;
    const int w32 = detect_w32(nm, mk, tid, &s_bad);
    if (blockIdx.x == 0 && tid == 0) *wflag = w32;

    const int t = blockIdx.x * 256 + tid;          // 0..16383
    pot8[t] = (unsigned char)boolat(nm, (long long)t * DD + COLIDX, w32);

    float cs = 0.0f, ms = 0.0f;
    if (!boolat(mk, (long long)t * DD + COLIDX, w32)) {
        cs = fitX[(long long)t * DD + COLIDX];
        ms = 1.0f;
    }
    sc[tid] = cs; sm[tid] = ms;
    __syncthreads();
#pragma unroll
    for (int s = 128; s > 0; s >>= 1) {
        if (tid < s) { sc[tid] += sc[tid + s]; sm[tid] += sm[tid + s]; }
        __syncthreads();
    }
    if (tid == 0) { partial[blockIdx.x * 2] = sc[0]; partial[blockIdx.x * 2 + 1] = sm[0]; }

    if (t < NQ) inmiss[t] = 0;
}

// ---------------------------------------------------------------------------
// prep2: 1 block — scatter row_missing_idx, finalize col_mean.
// ---------------------------------------------------------------------------
__global__ __launch_bounds__(256) void prep2_kernel(
    const int* __restrict__ rmi, const float* __restrict__ partial,
    float* __restrict__ cmean, unsigned char* __restrict__ inmiss)
{
    const int tid = threadIdx.x;
    for (int i = tid; i < NQ; i += 256) {
        int r = rmi[i];
        if (r >= 0 && r < NQ) inmiss[r] = 1;
    }
    if (tid == 0) {
        float c = 0.0f, m = 0.0f;
        for (int b = 0; b < 64; ++b) { c += partial[2 * b]; m += partial[2 * b + 1]; }
        *cmean = c / (m > 0.0f ? m : 1.0f);
    }
}

// ---------------------------------------------------------------------------
// Branchless top-5 maintenance. All indices compile-time -> pure VGPRs.
// ---------------------------------------------------------------------------
// Scan-order insert: strict < (ids strictly increase per thread, so equal
// keys keep the earlier index automatically).
__device__ __forceinline__ void insert_scan(float key, int t, float v[5], int id[5]) {
    const bool c0 = key < v[0];
    const bool c1 = key < v[1];
    const bool c2 = key < v[2];
    const bool c3 = key < v[3];
    const bool c4 = key < v[4];
    v[4] = c4 ? (c3 ? v[3] : key) : v[4];  id[4] = c4 ? (c3 ? id[3] : t) : id[4];
    v[3] = c3 ? (c2 ? v[2] : key) : v[3];  id[3] = c3 ? (c2 ? id[2] : t) : id[3];
    v[2] = c2 ? (c1 ? v[1] : key) : v[2];  id[2] = c2 ? (c1 ? id[1] : t) : id[2];
    v[1] = c1 ? (c0 ? v[0] : key) : v[1];  id[1] = c1 ? (c0 ? id[0] : t) : id[1];
    v[0] = c0 ? key : v[0];                id[0] = c0 ? t : id[0];
}

// Merge insert with full tie-break (lower index wins on equal key), matching
// jax.lax.top_k ordering. Keys are never NaN by construction.
__device__ __forceinline__ void insert_merge(float key, int t, float v[5], int id[5]) {
    const bool c0 = (key < v[0]) || (key == v[0] && t < id[0]);
    const bool c1 = (key < v[1]) || (key == v[1] && t < id[1]);
    const bool c2 = (key < v[2]) || (key == v[2] && t < id[2]);
    const bool c3 = (key < v[3]) || (key == v[3] && t < id[3]);
    const bool c4 = (key < v[4]) || (key == v[4] && t < id[4]);
    v[4] = c4 ? (c3 ? v[3] : key) : v[4];  id[4] = c4 ? (c3 ? id[3] : t) : id[4];
    v[3] = c3 ? (c2 ? v[2] : key) : v[3];  id[3] = c3 ? (c2 ? id[2] : t) : id[3];
    v[2] = c2 ? (c1 ? v[1] : key) : v[2];  id[2] = c2 ? (c1 ? id[1] : t) : id[2];
    v[1] = c1 ? (c0 ? v[0] : key) : v[1];  id[1] = c1 ? (c0 ? id[0] : t) : id[1];
    v[0] = c0 ? key : v[0];                id[0] = c0 ? t : id[0];
}

// ---------------------------------------------------------------------------
// Main kernel: one block (256 thr) per query row. Each thread scans 64
// elements via float4 with depth-2 prefetch; branchless top-5; wave shuffle
// merge; LDS cross-wave merge; thread-0 epilogue.
// ---------------------------------------------------------------------------
__global__ __launch_bounds__(256) void impute_kernel(
    const float* __restrict__ X,
    const float* __restrict__ dist,
    const void* __restrict__ maskp,
    const void* __restrict__ mkfitp,
    const float* __restrict__ fitX,
    const int* __restrict__ dmap,
    const int* __restrict__ wflagp,
    const float* __restrict__ cmeanp,
    const unsigned char* __restrict__ inmiss,
    const unsigned char* __restrict__ pot8,
    float* __restrict__ out)
{
    const int i = blockIdx.x;
    const int tid = threadIdx.x;

    if (tid < DD)
        out[(long long)i * DD + tid] = X[(long long)i * DD + tid];

    const int q = dmap[i];
    const float4* drow = (const float4*)(dist + (long long)q * NT);
    const uchar4* prow = (const uchar4*)pot8;

    float v[5]; int id[5];
#pragma unroll
    for (int k = 0; k < 5; ++k) { v[k] = INFF; id[k] = 0x7fffffff; }
    bool hv = false;

    float4 dv0 = drow[tid];
    uchar4 pv0 = prow[tid];
    float4 dv1 = drow[256 + tid];
    uchar4 pv1 = prow[256 + tid];

#pragma unroll
    for (int it = 0; it < 16; ++it) {
        const float4 dc = dv0; const uchar4 pc = pv0;
        dv0 = dv1; pv0 = pv1;
        if (it < 14) {
            dv1 = drow[(it + 2) * 256 + tid];
            pv1 = prow[(it + 2) * 256 + tid];
        }
        const int base = (it * 256 + tid) * 4;
        const float dj[4] = { dc.x, dc.y, dc.z, dc.w };
        const unsigned char pj[4] = { pc.x, pc.y, pc.z, pc.w };
#pragma unroll
        for (int j = 0; j < 4; ++j) {
            const bool pot = pj[j] != 0;
            const bool nn = (dj[j] == dj[j]);            // !isnan
            hv = hv || (pot && nn);
            const float key = pot ? (nn ? dj[j] : BIGF) : INFF;
            insert_scan(key, base + j, v, id);
        }
    }

    // wave-level merge (64 lanes -> lane 0)
#pragma unroll
    for (int off = 32; off >= 1; off >>= 1) {
        float v2[5]; int id2[5];
#pragma unroll
        for (int k = 0; k < 5; ++k) {
            v2[k] = __shfl_down(v[k], off);
            id2[k] = __shfl_down(id[k], off);
        }
#pragma unroll
        for (int k = 0; k < 5; ++k) insert_merge(v2[k], id2[k], v, id);
    }
    const bool whv = __any(hv);

    __shared__ float sv[4][5];
    __shared__ int   sid[4][5];
    __shared__ int   shv[4];
    const int wave = tid >> 6;
    const int lane = tid & 63;
    if (lane == 0) {
#pragma unroll
        for (int k = 0; k < 5; ++k) { sv[wave][k] = v[k]; sid[wave][k] = id[k]; }
        shv[wave] = whv ? 1 : 0;
    }
    __syncthreads();

    if (tid == 0) {
#pragma unroll
        for (int wv = 1; wv < 4; ++wv) {
#pragma unroll
            for (int k = 0; k < 5; ++k) insert_merge(sv[wv][k], sid[wv][k], v, id);
        }
        const int w32 = *wflagp;
        const bool has_valid = (shv[0] | shv[1] | shv[2] | shv[3]) != 0;
        const bool receiver =
            inmiss[i] && boolat(maskp, (long long)i * DD + COLIDX, w32);

        float val;
        if (!receiver) {
            val = X[(long long)i * DD + COLIDX];
        } else if (!has_valid) {
            val = *cmeanp;
        } else {
            float wk[5], dnr[5], dmv[5], vld[5];
            bool infrow = false;
#pragma unroll
            for (int k = 0; k < 5; ++k) {
                const int idx = id[k];
                const bool ok = (idx >= 0) && (idx < NT);
                const float key = v[k];
                // reconstruct d_pot: key==BIGF means original was NaN
                const float dpot = (key == BIGF) ? __builtin_nanf("") : key;
                const float t = 1.0f / dpot;   // 0 -> inf, inf -> 0, NaN -> NaN
                wk[k] = ok ? t : 0.0f;
                if (ok && isinf(t)) infrow = true;
                dnr[k] = ok ? fitX[(long long)idx * DD + COLIDX] : 0.0f;
                dmv[k] = ok ? (1.0f - (float)boolat(mkfitp, (long long)idx * DD + COLIDX, w32))
                            : 0.0f;
                vld[k] = ok ? (float)pot8[idx] : 0.0f;
            }
            if (infrow) {
#pragma unroll
                for (int k = 0; k < 5; ++k) wk[k] = isinf(wk[k]) ? 1.0f : 0.0f;
            }
#pragma unroll
            for (int k = 0; k < 5; ++k) if (wk[k] != wk[k]) wk[k] = 0.0f;

            float wsum = 0.0f, vsum = 0.0f;
#pragma unroll
            for (int k = 0; k < 5; ++k) {
                const float nw = dmv[k] * wk[k] * vld[k];
                wsum += nw;
                vsum += dnr[k] * nw;
            }
            const float div = (wsum == 0.0f) ? 1.0f : wsum;
            val = vsum / div;
        }
        out[(long long)i * DD + COLIDX] = val;
    }
}

extern "C" void kernel_launch(void* const* d_in, const int* in_sizes, int n_in,
                              void* d_out, int out_size, void* d_ws, size_t ws_size,
                              hipStream_t stream) {
    const float* X     = (const float*)d_in[0];
    const float* dist  = (const float*)d_in[1];
    const void*  nm    = d_in[2];   // non_missing_fix_X (bool)
    const void*  mkfit = d_in[3];   // mask_fit_X (bool)
    const int*   dmap  = (const int*)d_in[4];
    const void*  maskp = d_in[5];   // mask (bool)
    const int*   rmi   = (const int*)d_in[6];
    const float* fitX  = (const float*)d_in[7];
    float* out = (float*)d_out;

    int*   wflag   = (int*)d_ws;
    float* cmean   = (float*)((char*)d_ws + 4);
    float* partial = (float*)((char*)d_ws + 8);            // 64*2 floats = 512 B
    unsigned char* inmiss = (unsigned char*)d_ws + 520;    // NQ bytes
    unsigned char* pot8   = (unsigned char*)d_ws + 520 + NQ; // NT bytes, 4-aligned

    prep1_kernel<<<64, 256, 0, stream>>>(nm, mkfit, fitX, wflag, partial, inmiss, pot8);
    prep2_kernel<<<1, 256, 0, stream>>>(rmi, partial, cmean, inmiss);
    impute_kernel<<<NQ, 256, 0, stream>>>(X, dist, maskp, mkfit, fitX, dmap,
                                          wflag, cmean, inmiss, pot8, out);
}